// Round 10
// baseline (206.731 us; speedup 1.0000x reference)
//
#include <hip/hip_runtime.h>

namespace {

constexpr int FHc = 3, FWc = 3;
constexpr int Bc = 8, Cc = 32, Hc = 32, Wc = 32, Oc = 64;
constexpr int HOc = 30, WOc = 30;
constexpr float SHIFTc = 0.1f;
constexpr int ROWW = 12;                 // padded LDS row (10 used) -> 48B
constexpr int TILE_F = Cc * FHc * ROWW;  // 1152 floats per (lp|ln) tile

#define LOADROW(dst, base) do {                                         \
    const float4 _a = *reinterpret_cast<const float4*>(base);           \
    const float4 _b = *reinterpret_cast<const float4*>((base) + 4);     \
    const float2 _c = *reinterpret_cast<const float2*>((base) + 8);     \
    dst[0]=_a.x; dst[1]=_a.y; dst[2]=_a.z; dst[3]=_a.w;                 \
    dst[4]=_b.x; dst[5]=_b.y; dst[6]=_b.z; dst[7]=_b.w;                 \
    dst[8]=_c.x; dst[9]=_c.y; } while (0)

// R9 structure + INSTRUMENT: the fold pass runs TWICE (compile-time unrolled,
// asm-opacity on accumulators between passes so neither scratch nor CSE).
// Max is idempotent -> output bit-identical; main phase ~doubles -> kernel
// rises above the 38us poison-fills into the rocprof top-5 for real counters.
__global__ __launch_bounds__(512, 4)
void bipolar_morph2d(const float* __restrict__ x,
                     const float* __restrict__ k1,
                     const float* __restrict__ k2,
                     const float* __restrict__ bias,
                     float* __restrict__ out)
{
    __shared__ float sh[8192];           // 32 KiB: tiles, then reduce buffer
    float* lp = sh;
    float* ln = sh + TILE_F;

    const int tid = threadIdx.x;
    const int bid = blockIdx.x;
    const int wt  = bid & 3;             // wo-tile of 8
    const int ho  = (bid >> 2) % HOc;
    const int b   = bid / (4 * HOc);
    const int wo0 = wt * 8;

    // ---- stage: lp = log(max(x,.1)), ln = log(max(-x,.1)), 3x10 x C halo ----
    for (int e = tid; e < Cc * FHc * 10; e += 512) {
        const int c   = e / 30;
        const int rem = e - c * 30;
        const int i   = rem / 10;
        const int w   = rem - i * 10;
        int col = wo0 + w; if (col > Wc - 1) col = Wc - 1;  // clamp feeds only unused s
        const float xv = x[((b * Cc + c) * Hc + (ho + i)) * Wc + col];
        lp[(c * FHc + i) * ROWW + w] = __logf(fmaxf(xv,  SHIFTc));
        ln[(c * FHc + i) * ROWW + w] = __logf(fmaxf(-xv, SHIFTc));
    }
    __syncthreads();

    const int wv    = tid >> 6;          // 0..7
    const int o     = tid & 63;          // lane = output channel
    const int half  = wv >> 2;           // 0: lp (y11,y12)  1: ln (y21,y22)
    const int cw    = wv & 3;            // c-chunk of 8
    const int cbase = cw * 8;
    const float* tile = half ? ln : lp;
    const float* kt1  = k1 + o;          // lane-offset bases; idx = i*6144+j*2048+c*64
    const float* kt2  = k2 + o;

    float m1[8], m2[8];
    #pragma unroll
    for (int s = 0; s < 8; ++s) m1[s] = m2[s] = -1e30f;

    auto fold_pass = [&]() {
        #pragma unroll
        for (int p = 0; p < 4; ++p) {    // channel pairs
            const int c0 = cbase + 2 * p;
            #pragma unroll
            for (int i = 0; i < FHc; ++i) {
                float r0[10], r1[10];
                LOADROW(r0, &tile[(c0 * FHc + i) * ROWW]);
                LOADROW(r1, &tile[((c0 + 1) * FHc + i) * ROWW]);

                const int kb = i * 6144 + c0 * 64;   // j-stride 2048, c-stride 64
                const float a10 = kt1[kb],      a11 = kt1[kb + 2048], a12 = kt1[kb + 4096];
                const float b10 = kt1[kb + 64], b11 = kt1[kb + 2112], b12 = kt1[kb + 4160];
                const float a20 = kt2[kb],      a21 = kt2[kb + 2048], a22 = kt2[kb + 4096];
                const float b20 = kt2[kb + 64], b21 = kt2[kb + 2112], b22 = kt2[kb + 4160];

                #pragma unroll
                for (int s = 0; s < 8; ++s) {
                    m1[s] = fmaxf(fmaxf(m1[s], r0[s] + a10),     r0[s + 1] + a11);
                    m1[s] = fmaxf(fmaxf(m1[s], r0[s + 2] + a12), r1[s]     + b10);
                    m1[s] = fmaxf(fmaxf(m1[s], r1[s + 1] + b11), r1[s + 2] + b12);
                    m2[s] = fmaxf(fmaxf(m2[s], r0[s] + a20),     r0[s + 1] + a21);
                    m2[s] = fmaxf(fmaxf(m2[s], r0[s + 2] + a22), r1[s]     + b20);
                    m2[s] = fmaxf(fmaxf(m2[s], r1[s + 1] + b21), r1[s + 2] + b22);
                }
            }
        }
    };

    fold_pass();
    // opacity barrier: accs become opaque -> pass 2 cannot be CSE-collapsed,
    // values stay in VGPRs (no scratch; cf. R7 failure with runtime trip count)
    #pragma unroll
    for (int s = 0; s < 8; ++s) asm volatile("" : "+v"(m1[s]), "+v"(m2[s]));
    fold_pass();   // idempotent re-fold: output unchanged, main phase doubled

    // ---- publish partials: [half*2+table][cw][s][o] = 16*8*64 = 8192 floats ----
    __syncthreads();                     // tile reads done; overwrite sh
    #pragma unroll
    for (int s = 0; s < 8; ++s) {
        sh[(((half * 2 + 0) * 4 + cw) * 8 + s) * 64 + o] = m1[s];
        sh[(((half * 2 + 1) * 4 + cw) * 8 + s) * 64 + o] = m2[s];
    }
    __syncthreads();

    // ---- finalize: wave wv owns spatial position s = wv ----
    const int s  = wv;
    const int wo = wo0 + s;
    if (wo < WOc) {
        float f[4];
        #pragma unroll
        for (int g = 0; g < 4; ++g) {    // g: 0=y11 1=y12 2=y21 3=y22
            const float v0 = sh[((g * 4 + 0) * 8 + s) * 64 + o];
            const float v1 = sh[((g * 4 + 1) * 8 + s) * 64 + o];
            const float v2 = sh[((g * 4 + 2) * 8 + s) * 64 + o];
            const float v3 = sh[((g * 4 + 3) * 8 + s) * 64 + o];
            f[g] = fmaxf(fmaxf(v0, v1), fmaxf(v2, v3));
        }
        out[((b * Oc + o) * HOc + ho) * WOc + wo] =
            __expf(f[0]) - __expf(f[1]) - __expf(f[2]) + __expf(f[3]) + bias[o];
    }
}

} // namespace

extern "C" void kernel_launch(void* const* d_in, const int* in_sizes, int n_in,
                              void* d_out, int out_size, void* d_ws, size_t ws_size,
                              hipStream_t stream) {
    const float* x    = (const float*)d_in[0];
    const float* k1   = (const float*)d_in[1];
    const float* k2   = (const float*)d_in[2];
    const float* bias = (const float*)d_in[3];
    float* out        = (float*)d_out;

    const int nblocks = Bc * HOc * 4;   // 960
    bipolar_morph2d<<<dim3(nblocks), dim3(512), 0, stream>>>(x, k1, k2, bias, out);
}